// Round 17
// baseline (185.213 us; speedup 1.0000x reference)
//
#include <hip/hip_runtime.h>
#include <hip/hip_bf16.h>

// NodeFormerConv: Performer/Gumbel attention. fp32-equivalent math, fp32 output.
//   k_prep: split Wq|Wk|Wv, proj, Wo into MFMA-fragment-ordered hi/lo bf16
//   (k0   zero kvs/kssum — only in atomic-fallback mode)
//   k1   per 16-row tile, MFMA: QKV gemm (V held in regs); phi gemm; diag/rowmax/
//        exp in-register; v16/qp16/p16 staged in LDS and flushed coalesced
//   k2   MFMA accumulate; CH chunks/head (256 if ws fits); headmax in-kernel;
//        kp = RATIO*(p16*scaleAll[tile] + NEPS); flush -> bf16 slab (or atomics)
//   k2r  (mode 1) reduce CH bf16 slabs/head -> kssum + fragment-ordered Bfh/Bfl
//   k2b  (mode 0 only) split kvs into fragments
//   k3   per 32-row block: den up front; per head {B-frags, NUM MFMA, in-register
//        idl scale, part -> zsl[32][68], Wo MFMA for this head into o}; store o+bo

#define NEPS  1e-6f
#define RATIO 0.18257418583505536f   // 1/sqrt(30)
#define DNORM 0.35355339059327378f   // 64^-0.25

typedef __attribute__((ext_vector_type(8))) short short8;
typedef __attribute__((ext_vector_type(4))) float floatx4;

__device__ inline unsigned short f2bf(float x) {
    __hip_bfloat16 b = __float2bfloat16(x);
    return __builtin_bit_cast(unsigned short, b);
}
__device__ inline float bf2f(unsigned short h) {
    return __builtin_bit_cast(float, (unsigned int)h << 16);
}
__device__ inline void split2(float v, unsigned short& hi, unsigned short& lo) {
    unsigned short h = f2bf(v);
    hi = h; lo = f2bf(v - bf2f(h));
}

__global__ __launch_bounds__(256) void k0_zero(float* __restrict__ p, int count) {
    int id = blockIdx.x * 256 + threadIdx.x;
    if (id < count) p[id] = 0.f;
}

// ---- k_prep: fragment-ordered hi/lo splits (unchanged) ----
__global__ __launch_bounds__(256) void k_prep(
    const float* __restrict__ Wq, const float* __restrict__ Wk, const float* __restrict__ Wv,
    const float* __restrict__ proj, const float* __restrict__ Wo,
    unsigned short* __restrict__ Wfh, unsigned short* __restrict__ Wfl,
    unsigned short* __restrict__ Pfh, unsigned short* __restrict__ Pfl,
    unsigned short* __restrict__ Wofh, unsigned short* __restrict__ Wofl)
{
    const int b = blockIdx.x, t = threadIdx.x;
    if (b < 24) {
        const int slot = b * 256 + t;
        const int lane = slot & 63;
        const int ctks = slot >> 6;
        const int ct = ctks >> 1, ks = ctks & 1;
        const int col = ct * 16 + (lane & 15);
        const int k0 = ks * 32 + (lane >> 4) * 8;
        const float* W = (col < 256) ? Wq : (col < 512) ? Wk : Wv;
        const int cm = col & 255;
#pragma unroll
        for (int j = 0; j < 8; ++j) {
            float w = W[(k0 + j) * 256 + cm];
            unsigned short hi, lo; split2(w, hi, lo);
            Wfh[slot * 8 + j] = hi;
            Wfl[slot * 8 + j] = lo;
        }
    } else if (b == 24) {
        const int lane = t & 63;
        const int ctks = t >> 6;
        const int ct2 = ctks >> 1, ks = ctks & 1;
        const int m = ct2 * 16 + (lane & 15);
        const int k0 = ks * 32 + (lane >> 4) * 8;
#pragma unroll
        for (int j = 0; j < 8; ++j) {
            float p = (m < 30) ? proj[m * 64 + k0 + j] : 0.f;
            unsigned short hi, lo; split2(p, hi, lo);
            Pfh[t * 8 + j] = hi;
            Pfl[t * 8 + j] = lo;
        }
    } else {
        for (int idx = t; idx < 2048; idx += 256) {
            const int slot = idx >> 6, l = idx & 63;
            const int ct = slot >> 3, ks = slot & 7;
            const int col = ct * 16 + (l & 15);
            const int k0 = ks * 32 + (l >> 4) * 8;
#pragma unroll
            for (int j = 0; j < 8; ++j) {
                float w = Wo[(k0 + j) * 64 + col];
                unsigned short hi, lo; split2(w, hi, lo);
                Wofh[slot * 512 + l * 8 + j] = hi;
                Wofl[slot * 512 + l * 8 + j] = lo;
            }
        }
    }
}

// ---- k1: per 16-row tile; coalesced staged stores (unchanged from round 16) ----
__global__ __launch_bounds__(256) void k1_feat(
    const float* __restrict__ z,
    const float* __restrict__ bq, const float* __restrict__ bk, const float* __restrict__ bv,
    const unsigned short* __restrict__ Wfh, const unsigned short* __restrict__ Wfl,
    const unsigned short* __restrict__ Pfh, const unsigned short* __restrict__ Pfl,
    const float* __restrict__ tau,
    __hip_bfloat16* __restrict__ qp16, __hip_bfloat16* __restrict__ v16,
    __hip_bfloat16* __restrict__ p16, float* __restrict__ blockmax, int N)
{
    __shared__ alignas(16) unsigned short zh[16 * 72];
    __shared__ alignas(16) unsigned short zl_[16 * 72];
    __shared__ alignas(16) float qd[16 * 268];
    __shared__ alignas(16) float kd[16 * 268];

    unsigned short* vsS = reinterpret_cast<unsigned short*>(qd);
    unsigned short* qpS = vsS + 4096;
    unsigned short* ppS = qpS + 1920;

    const int t = threadIdx.x;
    const int n0 = blockIdx.x * 16;
    const int wave = t >> 6, lane = t & 63;
    const int l15 = lane & 15, l4 = lane >> 4;
    const float dsc = rsqrtf(tau[0]) * DNORM;

    for (int i = t; i < 1024; i += 256) {
        int r = i >> 6, c = i & 63;
        float v = (n0 + r < N) ? z[(long)(n0 + r) * 64 + c] : 0.f;
        unsigned short hi, lo; split2(v, hi, lo);
        zh[r * 72 + c] = hi;
        zl_[r * 72 + c] = lo;
    }
    __syncthreads();

    float accv[4][4];
    {
        const int abase = l15 * 72 + l4 * 8;
        short8 ah0 = *reinterpret_cast<const short8*>(&zh[abase]);
        short8 ah1 = *reinterpret_cast<const short8*>(&zh[abase + 32]);
        short8 al0 = *reinterpret_cast<const short8*>(&zl_[abase]);
        short8 al1 = *reinterpret_cast<const short8*>(&zl_[abase + 32]);
        const int row0 = l4 * 4;
#define QKV_MFMA(ci_)                                                                   \
        floatx4 acc = floatx4{0.f, 0.f, 0.f, 0.f};                                      \
        {                                                                               \
            const int ct = wave + 4 * (ci_);                                            \
            short8 bh0 = *reinterpret_cast<const short8*>(&Wfh[(ct * 2 + 0) * 512 + lane * 8]); \
            short8 bh1 = *reinterpret_cast<const short8*>(&Wfh[(ct * 2 + 1) * 512 + lane * 8]); \
            short8 bl0 = *reinterpret_cast<const short8*>(&Wfl[(ct * 2 + 0) * 512 + lane * 8]); \
            short8 bl1 = *reinterpret_cast<const short8*>(&Wfl[(ct * 2 + 1) * 512 + lane * 8]); \
            acc = __builtin_amdgcn_mfma_f32_16x16x32_bf16(ah0, bh0, acc, 0, 0, 0);      \
            acc = __builtin_amdgcn_mfma_f32_16x16x32_bf16(ah1, bh1, acc, 0, 0, 0);      \
            acc = __builtin_amdgcn_mfma_f32_16x16x32_bf16(ah0, bl0, acc, 0, 0, 0);      \
            acc = __builtin_amdgcn_mfma_f32_16x16x32_bf16(ah1, bl1, acc, 0, 0, 0);      \
            acc = __builtin_amdgcn_mfma_f32_16x16x32_bf16(al0, bh0, acc, 0, 0, 0);      \
            acc = __builtin_amdgcn_mfma_f32_16x16x32_bf16(al1, bh1, acc, 0, 0, 0);      \
        }
#pragma unroll 2
        for (int ci = 0; ci < 4; ++ci) {
            QKV_MFMA(ci)
            const int c = (wave + 4 * ci) * 16 + l15;
            const float bb = bq[c];
#pragma unroll
            for (int r = 0; r < 4; ++r) qd[(row0 + r) * 268 + c] = (acc[r] + bb) * dsc;
        }
#pragma unroll 2
        for (int ci = 4; ci < 8; ++ci) {
            QKV_MFMA(ci)
            const int c = (wave + 4 * ci) * 16 + l15 - 256;
            const float bb = bk[c];
#pragma unroll
            for (int r = 0; r < 4; ++r) kd[(row0 + r) * 268 + c] = (acc[r] + bb) * dsc;
        }
#pragma unroll
        for (int ci = 8; ci < 12; ++ci) {
            QKV_MFMA(ci)
            const int c = (wave + 4 * ci) * 16 + l15 - 512;
            const float bb = bv[c];
#pragma unroll
            for (int r = 0; r < 4; ++r) accv[ci - 8][r] = acc[r] + bb;
        }
#undef QKV_MFMA
    }
    __syncthreads();

    {
        short8 pbh[2][2], pbl[2][2];
#pragma unroll
        for (int ct2 = 0; ct2 < 2; ++ct2)
#pragma unroll
            for (int ks = 0; ks < 2; ++ks) {
                pbh[ct2][ks] = *reinterpret_cast<const short8*>(&Pfh[(ct2 * 2 + ks) * 512 + lane * 8]);
                pbl[ct2][ks] = *reinterpret_cast<const short8*>(&Pfl[(ct2 * 2 + ks) * 512 + lane * 8]);
            }
        const int h = wave;
        const int row0 = l4 * 4;
        const int rbase = l15 * 268 + h * 64 + l4 * 8;
        float xq[8], yq[8], xk[8], yk[8];
        {
            float4 a0 = *reinterpret_cast<const float4*>(&qd[rbase]);
            float4 a1 = *reinterpret_cast<const float4*>(&qd[rbase + 4]);
            float4 a2 = *reinterpret_cast<const float4*>(&qd[rbase + 32]);
            float4 a3 = *reinterpret_cast<const float4*>(&qd[rbase + 36]);
            xq[0]=a0.x; xq[1]=a0.y; xq[2]=a0.z; xq[3]=a0.w;
            xq[4]=a1.x; xq[5]=a1.y; xq[6]=a1.z; xq[7]=a1.w;
            yq[0]=a2.x; yq[1]=a2.y; yq[2]=a2.z; yq[3]=a2.w;
            yq[4]=a3.x; yq[5]=a3.y; yq[6]=a3.z; yq[7]=a3.w;
            float4 b0 = *reinterpret_cast<const float4*>(&kd[rbase]);
            float4 b1 = *reinterpret_cast<const float4*>(&kd[rbase + 4]);
            float4 b2 = *reinterpret_cast<const float4*>(&kd[rbase + 32]);
            float4 b3 = *reinterpret_cast<const float4*>(&kd[rbase + 36]);
            xk[0]=b0.x; xk[1]=b0.y; xk[2]=b0.z; xk[3]=b0.w;
            xk[4]=b1.x; xk[5]=b1.y; xk[6]=b1.z; xk[7]=b1.w;
            yk[0]=b2.x; yk[1]=b2.y; yk[2]=b2.z; yk[3]=b2.w;
            yk[4]=b3.x; yk[5]=b3.y; yk[6]=b3.z; yk[7]=b3.w;
        }
        __syncthreads();

        // ---- q side ----
        {
            float diag;
            {
                float s = 0.f;
#pragma unroll
                for (int j = 0; j < 8; ++j) s += xq[j] * xq[j] + yq[j] * yq[j];
                s += __shfl_xor(s, 16);
                s += __shfl_xor(s, 32);
                diag = 0.5f * s;
            }
            short8 ah0, al0, ah1, al1;
#pragma unroll
            for (int j = 0; j < 8; ++j) {
                unsigned short hi, lo;
                split2(xq[j], hi, lo); ah0[j] = (short)hi; al0[j] = (short)lo;
                split2(yq[j], hi, lo); ah1[j] = (short)hi; al1[j] = (short)lo;
            }
            floatx4 acc2[2];
#pragma unroll
            for (int ct2 = 0; ct2 < 2; ++ct2) {
                floatx4 acc = floatx4{0.f, 0.f, 0.f, 0.f};
                acc = __builtin_amdgcn_mfma_f32_16x16x32_bf16(ah0, pbh[ct2][0], acc, 0, 0, 0);
                acc = __builtin_amdgcn_mfma_f32_16x16x32_bf16(ah1, pbh[ct2][1], acc, 0, 0, 0);
                acc = __builtin_amdgcn_mfma_f32_16x16x32_bf16(ah0, pbl[ct2][0], acc, 0, 0, 0);
                acc = __builtin_amdgcn_mfma_f32_16x16x32_bf16(ah1, pbl[ct2][1], acc, 0, 0, 0);
                acc = __builtin_amdgcn_mfma_f32_16x16x32_bf16(al0, pbh[ct2][0], acc, 0, 0, 0);
                acc = __builtin_amdgcn_mfma_f32_16x16x32_bf16(al1, pbh[ct2][1], acc, 0, 0, 0);
                acc2[ct2] = acc;
            }
#pragma unroll
            for (int r = 0; r < 4; ++r) {
                float a1 = (l15 >= 14) ? -3.4e38f : acc2[1][r];
                float v = fmaxf(acc2[0][r], a1);
                v = fmaxf(v, __shfl_xor(v, 1));
                v = fmaxf(v, __shfl_xor(v, 2));
                v = fmaxf(v, __shfl_xor(v, 4));
                v = fmaxf(v, __shfl_xor(v, 8));
#pragma unroll
                for (int ct2 = 0; ct2 < 2; ++ct2) {
                    const int m = ct2 * 16 + l15;
                    if (m < 30)
                        qpS[(row0 + r) * 120 + h * 30 + m] =
                            f2bf(RATIO * (__expf(acc2[ct2][r] - diag - v) + NEPS));
                }
            }
        }
        // ---- k side ----
        {
            float diag;
            {
                float s = 0.f;
#pragma unroll
                for (int j = 0; j < 8; ++j) s += xk[j] * xk[j] + yk[j] * yk[j];
                s += __shfl_xor(s, 16);
                s += __shfl_xor(s, 32);
                diag = 0.5f * s;
            }
            short8 ah0, al0, ah1, al1;
#pragma unroll
            for (int j = 0; j < 8; ++j) {
                unsigned short hi, lo;
                split2(xk[j], hi, lo); ah0[j] = (short)hi; al0[j] = (short)lo;
                split2(yk[j], hi, lo); ah1[j] = (short)hi; al1[j] = (short)lo;
            }
            floatx4 acc2[2];
#pragma unroll
            for (int ct2 = 0; ct2 < 2; ++ct2) {
                floatx4 acc = floatx4{0.f, 0.f, 0.f, 0.f};
                acc = __builtin_amdgcn_mfma_f32_16x16x32_bf16(ah0, pbh[ct2][0], acc, 0, 0, 0);
                acc = __builtin_amdgcn_mfma_f32_16x16x32_bf16(ah1, pbh[ct2][1], acc, 0, 0, 0);
                acc = __builtin_amdgcn_mfma_f32_16x16x32_bf16(ah0, pbl[ct2][0], acc, 0, 0, 0);
                acc = __builtin_amdgcn_mfma_f32_16x16x32_bf16(ah1, pbl[ct2][1], acc, 0, 0, 0);
                acc = __builtin_amdgcn_mfma_f32_16x16x32_bf16(al0, pbh[ct2][0], acc, 0, 0, 0);
                acc = __builtin_amdgcn_mfma_f32_16x16x32_bf16(al1, pbh[ct2][1], acc, 0, 0, 0);
                acc2[ct2] = acc;
            }
            float vmax[4];
#pragma unroll
            for (int r = 0; r < 4; ++r) {
                float a1 = (l15 >= 14) ? -3.4e38f : acc2[1][r];
                float v = fmaxf(acc2[0][r], a1);
                v = fmaxf(v, __shfl_xor(v, 1));
                v = fmaxf(v, __shfl_xor(v, 2));
                v = fmaxf(v, __shfl_xor(v, 4));
                v = fmaxf(v, __shfl_xor(v, 8));
                vmax[r] = v;
            }
            float mv = -3.4e38f;
#pragma unroll
            for (int r = 0; r < 4; ++r)
                if (n0 + row0 + r < N) mv = fmaxf(mv, vmax[r]);
            mv = fmaxf(mv, __shfl_xor(mv, 16));
            mv = fmaxf(mv, __shfl_xor(mv, 32));
            if (lane == 0) blockmax[blockIdx.x * 4 + h] = mv;
#pragma unroll
            for (int ct2 = 0; ct2 < 2; ++ct2) {
                const int m = ct2 * 16 + l15;
                if (m < 30)
#pragma unroll
                    for (int r = 0; r < 4; ++r)
                        ppS[(row0 + r) * 120 + h * 30 + m] =
                            f2bf(__expf(acc2[ct2][r] - diag - mv));
            }
        }
#pragma unroll
        for (int ci = 8; ci < 12; ++ci) {
            const int cc = (wave + 4 * ci - 32) * 16 + l15;
#pragma unroll
            for (int r = 0; r < 4; ++r)
                vsS[(row0 + r) * 256 + cc] = f2bf(accv[ci - 8][r]);
        }
    }
    __syncthreads();

    {
        const uint4* vs4 = reinterpret_cast<const uint4*>(vsS);
        uint4* vg = reinterpret_cast<uint4*>(v16) + (long)n0 * 32;
        for (int i = t; i < 512; i += 256) {
            if (n0 + (i >> 5) < N) vg[i] = vs4[i];
        }
        const uint4* qs4 = reinterpret_cast<const uint4*>(qpS);
        uint4* qg = reinterpret_cast<uint4*>(qp16) + (long)n0 * 15;
        const uint4* ps4 = reinterpret_cast<const uint4*>(ppS);
        uint4* pg = reinterpret_cast<uint4*>(p16) + (long)n0 * 15;
        for (int i = t; i < 240; i += 256) {
            if (n0 + i / 15 < N) { qg[i] = qs4[i]; pg[i] = ps4[i]; }
        }
    }
}

// ---- k2: MFMA accumulate; CH chunks/head; bf16 slab flush (mode 1) ----
__global__ __launch_bounds__(256) void k2_kvs(
    const __hip_bfloat16* __restrict__ p16, const float* __restrict__ gum,
    const __hip_bfloat16* __restrict__ v16, const float* __restrict__ tau,
    const float* __restrict__ blockmax,
    float* __restrict__ kvs, float* __restrict__ kssum,
    unsigned short* __restrict__ part, int mode, int N, int nchunk, int ntiles, int CH)
{
    __shared__ alignas(16) unsigned short Vt[80 * 72];
    __shared__ float kpL[64 * 33];
    __shared__ alignas(16) float geT[13 * 72];
    __shared__ float scaleAll[32];
    __shared__ float redmx[256];

    const int t = threadIdx.x;
    const int h = blockIdx.x / CH;
    const int chunk = blockIdx.x % CH;
    const int n0 = chunk * nchunk;
    const int n1 = (n0 + nchunk < N) ? (n0 + nchunk) : N;
    const float itau = 1.0f / tau[0];
    const int wave = t >> 6, lane = t & 63;
    const int l15 = lane & 15, l4 = lane >> 4;
    const int tb0 = n0 >> 4;

    int pr_r[4], pr_m[4]; bool pvld[4];
#pragma unroll
    for (int u = 0; u < 4; ++u) {
        int i = t + 256 * u;
        pvld[u] = (i < 960);
        int ii = pvld[u] ? i : 959;
        pr_r[u] = (2 * ii) / 30;
        pr_m[u] = (2 * ii) % 30;
    }
    int gu_k[3], gu_n[3];
#pragma unroll
    for (int u = 0; u < 3; ++u) { int i = t + 256 * u; gu_k[u] = i >> 6; gu_n[u] = i & 63; }
    int v_n[8], v_dp[8];
#pragma unroll
    for (int u = 0; u < 8; ++u) { int i = t + 256 * u; v_n[u] = i >> 5; v_dp[u] = (i & 31) * 2; }

    unsigned int rp[4], rv[8];
    float rg[3];

    floatx4 acc[5][5];
#pragma unroll
    for (int q = 0; q < 5; ++q)
#pragma unroll
        for (int dt = 0; dt < 5; ++dt) acc[q][dt] = floatx4{0.f, 0.f, 0.f, 0.f};

    int mq[5], kq[5];
#pragma unroll
    for (int q = 0; q < 5; ++q) {
        int row = (wave * 5 + q) * 16 + l15;
        mq[q] = row % 30;
        kq[q] = row / 30;
    }

    if (t < 64) Vt[64 * 72 + t] = f2bf(1.0f);
    for (int i = t; i < 15 * 72; i += 256) Vt[65 * 72 + i] = 0;
    for (int i = t; i < 3 * 72; i += 256) geT[10 * 72 + i] = 0.f;

    const int ntile = (n1 > n0) ? ((n1 - n0 + 63) >> 6) : 0;

#define K2_LOAD(nb_)                                                              \
    do {                                                                          \
        _Pragma("unroll")                                                         \
        for (int u = 0; u < 4; ++u) {                                             \
            int n = (nb_) + pr_r[u]; n = (n < n1) ? n : (n1 - 1); n = (n < 0) ? 0 : n; \
            rp[u] = *reinterpret_cast<const unsigned int*>(                       \
                (const unsigned short*)p16 + (long)n * 120 + h * 30 + pr_m[u]);   \
        }                                                                         \
        _Pragma("unroll")                                                         \
        for (int u = 0; u < 3; ++u) {                                             \
            int n = (nb_) + gu_n[u]; n = (n < n1) ? n : (n1 - 1); n = (n < 0) ? 0 : n; \
            rg[u] = gum[(long)n * 40 + h * 10 + gu_k[u]];                         \
        }                                                                         \
        _Pragma("unroll")                                                         \
        for (int u = 0; u < 8; ++u) {                                             \
            int n = (nb_) + v_n[u]; n = (n < n1) ? n : (n1 - 1); n = (n < 0) ? 0 : n; \
            rv[u] = *reinterpret_cast<const unsigned int*>(                       \
                v16 + (long)n * 256 + h * 64 + v_dp[u]);                          \
        }                                                                         \
    } while (0)

    K2_LOAD(n0);

    // in-kernel headmax reduce
    {
        float lm = -3.4e38f;
        for (int i = t; i < ntiles; i += 256) lm = fmaxf(lm, blockmax[i * 4 + h]);
        redmx[t] = lm;
        __syncthreads();
#pragma unroll
        for (int s = 128; s > 0; s >>= 1) {
            if (t < s) redmx[t] = fmaxf(redmx[t], redmx[t + s]);
            __syncthreads();
        }
    }
    const float MX = redmx[0];
    if (t < 32) {
        int tid = tb0 + t;
        int maxtid = (N - 1) >> 4;
        if (tid > maxtid) tid = maxtid;
        scaleAll[t] = __expf(blockmax[tid * 4 + h] - MX);
    }

    for (int tt = 0; tt < ntile; ++tt) {
        const int nb = n0 + tt * 64;
        __syncthreads();
#pragma unroll
        for (int u = 0; u < 4; ++u) {
            if (pvld[u]) {
                bool ok = (nb + pr_r[u] < n1);
                float sc = scaleAll[((nb + pr_r[u]) >> 4) - tb0];
                float plo = bf2f((unsigned short)(rp[u] & 0xffffu));
                float phi = bf2f((unsigned short)(rp[u] >> 16));
                kpL[pr_r[u] * 33 + pr_m[u]]     = ok ? RATIO * (plo * sc + NEPS) : 0.f;
                kpL[pr_r[u] * 33 + pr_m[u] + 1] = ok ? RATIO * (phi * sc + NEPS) : 0.f;
            }
        }
#pragma unroll
        for (int u = 0; u < 3; ++u) {
            if (u < 2 || t < 128) {
                bool ok = (nb + gu_n[u] < n1);
                geT[gu_k[u] * 72 + gu_n[u]] = ok ? __expf(rg[u] * itau) : 0.f;
            }
        }
#pragma unroll
        for (int u = 0; u < 8; ++u) {
            bool ok = (nb + v_n[u] < n1);
            unsigned int uu = ok ? rv[u] : 0u;
            Vt[v_dp[u] * 72 + v_n[u]] = (unsigned short)(uu & 0xffffu);
            Vt[(v_dp[u] + 1) * 72 + v_n[u]] = (unsigned short)(uu >> 16);
        }
        __syncthreads();
        if (tt + 1 < ntile) K2_LOAD(nb + 64);

#pragma unroll
        for (int nh = 0; nh < 2; ++nh) {
            const int nbase = nh * 32 + l4 * 8;
            short8 b[5];
#pragma unroll
            for (int dt = 0; dt < 5; ++dt)
                b[dt] = *reinterpret_cast<const short8*>(&Vt[(dt * 16 + l15) * 72 + nbase]);
#pragma unroll
            for (int q = 0; q < 5; ++q) {
                float4 g0 = *reinterpret_cast<const float4*>(&geT[kq[q] * 72 + nbase]);
                float4 g1 = *reinterpret_cast<const float4*>(&geT[kq[q] * 72 + nbase + 4]);
                const float gg[8] = {g0.x, g0.y, g0.z, g0.w, g1.x, g1.y, g1.z, g1.w};
                short8 a;
#pragma unroll
                for (int j = 0; j < 8; ++j) {
                    float kp = kpL[(nbase + j) * 33 + mq[q]];
                    a[j] = (short)f2bf(kp * gg[j]);
                }
#pragma unroll
                for (int dt = 0; dt < 5; ++dt)
                    acc[q][dt] = __builtin_amdgcn_mfma_f32_16x16x32_bf16(a, b[dt], acc[q][dt], 0, 0, 0);
            }
        }
    }
#undef K2_LOAD

    if (mode) {
        unsigned short* slab = part + (long)blockIdx.x * 19520;
#pragma unroll
        for (int q = 0; q < 5; ++q) {
            const int kmb = (wave * 5 + q) * 16 + l4 * 4;
#pragma unroll
            for (int r = 0; r < 4; ++r) {
                const int km = kmb + r;
                if (km < 300) {
#pragma unroll
                    for (int dt = 0; dt < 4; ++dt)
                        slab[km * 64 + dt * 16 + l15] = f2bf(acc[q][dt][r]);
                    if (l15 == 0) slab[19200 + km] = f2bf(acc[q][4][r]);
                }
            }
        }
    } else {
        float* kvh = kvs + h * 19200;
#pragma unroll
        for (int q = 0; q < 5; ++q) {
            const int kmb = (wave * 5 + q) * 16 + l4 * 4;
#pragma unroll
            for (int r = 0; r < 4; ++r) {
                const int km = kmb + r;
                if (km < 300) {
#pragma unroll
                    for (int dt = 0; dt < 4; ++dt)
                        atomicAdd(&kvh[km * 64 + dt * 16 + l15], acc[q][dt][r]);
                    if (l15 == 0)
                        atomicAdd(&kssum[h * 300 + km], acc[q][4][r]);
                }
            }
        }
    }
}

// ---- k2r (mode 1): reduce CH bf16 slabs/head -> kssum + Bfh/Bfl direct ----
__global__ __launch_bounds__(256) void k2r_reduce(
    const unsigned short* __restrict__ part, float* __restrict__ kssum,
    unsigned short* __restrict__ Bfh, unsigned short* __restrict__ Bfl, int CH)
{
    const int b = blockIdx.x, t = threadIdx.x;
    if (b >= 305) {                                    // pad zeroing
        const int p = (b - 305) * 256 + t;             // < 5120
        const int j = 6 + (p & 1);
        const int q2 = p >> 1;
        const int l15 = q2 & 15;
        const int ct = (q2 >> 4) % 40;
        const int h = q2 / 640;
        const long idx = ((long)(h * 40 + ct) * 64 + 48 + l15) * 8 + j;
        Bfh[idx] = 0; Bfl[idx] = 0;
        return;
    }
    const int o = b * 256 + t;
    if (o >= 4 * 19504) return;
    const int h = o / 19504, e = o % 19504;
    const unsigned short* p = part + (long)h * CH * 19520 + e;
    float s = 0.f;
#pragma unroll 8
    for (int c = 0; c < CH; ++c) s += bf2f(p[(long)c * 19520]);
    if (e < 19200) {
        const int km = e >> 6, d = e & 63;
        const int k = km / 30, m = km % 30;
        const int col = k * 64 + d;
        const int ct = col >> 4;
        const int lane = ((m >> 3) << 4) | (d & 15);
        const int j = m & 7;
        const long idx = ((long)(h * 40 + ct) * 64 + lane) * 8 + j;
        unsigned short hi, lo; split2(s, hi, lo);
        Bfh[idx] = hi; Bfl[idx] = lo;
    } else if (e - 19200 < 300) {
        kssum[h * 300 + (e - 19200)] = s;
    }
}

// ---- k2b (mode 0 only) ----
__global__ __launch_bounds__(256) void k2b_frag(
    const float* __restrict__ kvs,
    unsigned short* __restrict__ Bfh, unsigned short* __restrict__ Bfl)
{
    const int slot = blockIdx.x * 256 + threadIdx.x;
    if (slot >= 10240) return;
    const int h = slot / 2560;
    const int rem = slot % 2560;
    const int ct = rem >> 6, lane = rem & 63;
    const int col = ct * 16 + (lane & 15);
    const int k = col >> 6, d = col & 63;
    const int mb = (lane >> 4) * 8;
    const float* src = kvs + h * 19200 + (k * 30 + mb) * 64 + d;
    short8 hi8, lo8;
#pragma unroll
    for (int j = 0; j < 8; ++j) {
        float v = (mb + j < 30) ? src[j * 64] : 0.f;
        unsigned short hh, ll; split2(v, hh, ll);
        hi8[j] = (short)hh; lo8[j] = (short)ll;
    }
    *reinterpret_cast<short8*>(&Bfh[(long)slot * 8]) = hi8;
    *reinterpret_cast<short8*>(&Bfl[(long)slot * 8]) = lo8;
}

// ---- k3: den up front; per head {B-frags, NUM MFMA, idl in-reg, zsl, Wo MFMA} ----
__global__ __launch_bounds__(512) void k3_out(
    const __hip_bfloat16* __restrict__ qp16,
    const unsigned short* __restrict__ Bfh, const unsigned short* __restrict__ Bfl,
    const float* __restrict__ kssum,
    const unsigned short* __restrict__ Wofh, const unsigned short* __restrict__ Wofl,
    const float* __restrict__ bo, float* __restrict__ out, int N)
{
    __shared__ alignas(16) unsigned short qpall[32 * 136];   //  8704 B
    __shared__ float ksall[1200];                            //  4800 B
    __shared__ float idla[4 * 320];                          //  5120 B
    __shared__ alignas(16) float part[2][32][68];            // 17408 B
    __shared__ alignas(16) float zsl[32][68];                //  8704 B

    const int t = threadIdx.x;
    const int n0 = blockIdx.x * 32;
    const int wave = t >> 6, lane = t & 63;
    const int g = wave & 3, khalf = wave >> 2;
    const int l15 = lane & 15, l4 = lane >> 4;

    for (int i = t; i < 1200; i += 512) ksall[i] = kssum[i];
    for (int i = t; i < 32 * 60; i += 512) {
        int rr = i / 60, dw = i % 60;
        int n = n0 + rr; if (n >= N) n = N - 1;
        unsigned int u = *reinterpret_cast<const unsigned int*>(
            (const unsigned short*)qp16 + (long)n * 120 + dw * 2);
        int h = dw / 15, md = (dw % 15) * 2;
        qpall[rr * 136 + h * 32 + md] = (unsigned short)(u & 0xffffu);
        qpall[rr * 136 + h * 32 + md + 1] = (unsigned short)(u >> 16);
    }
    __syncthreads();

    for (int i = t; i < 1280; i += 512) {
        int h = i / 320, rem = i % 320;
        int rr = rem / 10, kk = rem % 10;
        const unsigned short* qr = &qpall[rr * 136 + h * 32];
        const float* kr = &ksall[h * 300 + kk * 30];
        float s = 0.f;
#pragma unroll
        for (int m = 0; m < 30; ++m) s += bf2f(qr[m]) * kr[m];
        idla[i] = 1.0f / s;
    }
    __syncthreads();

    floatx4 o = floatx4{0.f, 0.f, 0.f, 0.f};   // accumulated over heads

    for (int h = 0; h < 4; ++h) {
        short8 bh[5], bl[5];
#pragma unroll
        for (int q = 0; q < 5; ++q) {
            const int ct = (khalf * 5 + q) * 4 + g;
            const long off = ((long)(h * 40 + ct) * 64 + lane) * 8;
            bh[q] = *reinterpret_cast<const short8*>(Bfh + off);
            bl[q] = *reinterpret_cast<const short8*>(Bfl + off);
        }
        short8 aQ[2];
#pragma unroll
        for (int rt = 0; rt < 2; ++rt) {
            const unsigned int* qrow = reinterpret_cast<const unsigned int*>(
                &qpall[(rt * 16 + l15) * 136 + h * 32 + l4 * 8]);
            short8 a;
#pragma unroll
            for (int jj = 0; jj < 4; ++jj) {
                unsigned int u = qrow[jj];
                a[jj * 2] = (short)(u & 0xffffu);
                a[jj * 2 + 1] = (short)(u >> 16);
            }
            if (l4 == 3) { a[6] = 0; a[7] = 0; }
            aQ[rt] = a;
        }
        floatx4 acc[2][5];
#pragma unroll
        for (int rt = 0; rt < 2; ++rt)
#pragma unroll
            for (int q = 0; q < 5; ++q) acc[rt][q] = floatx4{0.f, 0.f, 0.f, 0.f};
#pragma unroll
        for (int q = 0; q < 5; ++q) {
            acc[0][q] = __builtin_amdgcn_mfma_f32_16x16x32_bf16(aQ[0], bh[q], acc[0][q], 0, 0, 0);
            acc[0][q] = __builtin_amdgcn_mfma_f32_16x16x32_bf16(aQ[0], bl[q], acc[0][q], 0, 0, 0);
            acc[1][q] = __builtin_amdgcn_mfma_f32_16x16x32_bf16(aQ[1], bh[q], acc[1][q], 0, 0, 0);
            acc[1][q] = __builtin_amdgcn_mfma_f32_16x16x32_bf16(aQ[1], bl[q], acc[1][q], 0, 0, 0);
        }
#pragma unroll
        for (int rt = 0; rt < 2; ++rt)
#pragma unroll
            for (int r = 0; r < 4; ++r) {
                const int row = rt * 16 + l4 * 4 + r;
                float s = 0.f;
#pragma unroll
                for (int q = 0; q < 5; ++q)
                    s += acc[rt][q][r] * idla[h * 320 + row * 10 + khalf * 5 + q];
                part[khalf][row][g * 16 + l15] = s;
            }
        __syncthreads();                         // [A] part ready (also orders prev Wo reads vs zsl write)
        {
            const int row = t >> 4, d4 = t & 15;
            float4 p0 = *reinterpret_cast<const float4*>(&part[0][row][d4 * 4]);
            float4 p1 = *reinterpret_cast<const float4*>(&part[1][row][d4 * 4]);
            float4 zv;
            zv.x = 0.1f * (p0.x + p1.x); zv.y = 0.1f * (p0.y + p1.y);
            zv.z = 0.1f * (p0.z + p1.z); zv.w = 0.1f * (p0.w + p1.w);
            *reinterpret_cast<float4*>(&zsl[row][d4 * 4]) = zv;
        }
        __syncthreads();                         // [B] zsl ready (also frees part)
        // Wo MFMA for this head: wave -> (rt = khalf, ct = g)
#pragma unroll
        for (int ks = 0; ks < 2; ++ks) {
            const float* zr = &zsl[khalf * 16 + l15][ks * 32 + l4 * 8];
            float4 x0 = *reinterpret_cast<const float4*>(zr);
            float4 x1 = *reinterpret_cast<const float4*>(zr + 4);
            float xv[8] = {x0.x, x0.y, x0.z, x0.w, x1.x, x1.y, x1.z, x1.w};
            short8 ah, al;
#pragma unroll
            for (int j = 0; j < 8; ++j) {
                unsigned short hi, lo; split2(xv[j], hi, lo);
                ah[j] = (short)hi; al[j] = (short)lo;
            }
            const int slot = g * 8 + h * 2 + ks;
            short8 wbh = *reinterpret_cast<const short8*>(&Wofh[slot * 512 + lane * 8]);
            short8 wbl = *reinterpret_cast<const short8*>(&Wofl[slot * 512 + lane * 8]);
            o = __builtin_amdgcn_mfma_f32_16x16x32_bf16(ah, wbh, o, 0, 0, 0);
            o = __builtin_amdgcn_mfma_f32_16x16x32_bf16(ah, wbl, o, 0, 0, 0);
            o = __builtin_amdgcn_mfma_f32_16x16x32_bf16(al, wbh, o, 0, 0, 0);
        }
    }
    // epilogue: out tile (rt = khalf, ct = g)
    {
        const int col = g * 16 + l15;
        const float bb = bo[col];
#pragma unroll
        for (int r = 0; r < 4; ++r) {
            const int n = n0 + khalf * 16 + l4 * 4 + r;
            if (n < N) out[(long)n * 64 + col] = o[r] + bb;
        }
    }
}

extern "C" void kernel_launch(void* const* d_in, const int* in_sizes, int n_in,
                              void* d_out, int out_size, void* d_ws, size_t ws_size,
                              hipStream_t stream)
{
    const float* z    = (const float*)d_in[0];
    const float* Wq   = (const float*)d_in[1];
    const float* bq   = (const float*)d_in[2];
    const float* Wk   = (const float*)d_in[3];
    const float* bk   = (const float*)d_in[4];
    const float* Wv   = (const float*)d_in[5];
    const float* bv   = (const float*)d_in[6];
    const float* Wo   = (const float*)d_in[7];
    const float* bo   = (const float*)d_in[8];
    const float* proj = (const float*)d_in[9];
    const float* gum  = (const float*)d_in[10];
    const float* tau  = (const float*)d_in[11];
    float* out = (float*)d_out;

    const int N = in_sizes[0] / 64;          // 50000
    const int ntiles = (N + 15) / 16;        // 3125
    const int nblk3  = (N + 31) / 32;        // 1563

    char* wsb = (char*)d_ws;
    size_t off = 0;
    __hip_bfloat16* qp16 = (__hip_bfloat16*)(wsb);
    off += ((size_t)N * 120 * 2 + 255) & ~(size_t)255;
    __hip_bfloat16* v16 = (__hip_bfloat16*)(wsb + off);
    off += ((size_t)N * 256 * 2 + 255) & ~(size_t)255;
    __hip_bfloat16* p16 = (__hip_bfloat16*)(wsb + off);
    off += ((size_t)N * 120 * 2 + 255) & ~(size_t)255;
    float* kvs      = (float*)(wsb + off);
    float* kssum    = kvs + 76800;
    float* headmax  = kssum + 1200;
    float* blockmax = headmax + 4;
    off += ((size_t)(76800 + 1200 + 4 + (size_t)ntiles * 4) * 4 + 255) & ~(size_t)255;
    unsigned short* Wfh = (unsigned short*)(wsb + off); off += 49152 * 2;
    unsigned short* Wfl = (unsigned short*)(wsb + off); off += 49152 * 2;
    unsigned short* Pfh = (unsigned short*)(wsb + off); off += 2048 * 2;
    unsigned short* Pfl = (unsigned short*)(wsb + off); off += 2048 * 2;
    unsigned short* Wofh = (unsigned short*)(wsb + off); off += 16384 * 2;
    unsigned short* Wofl = (unsigned short*)(wsb + off); off += 16384 * 2;
    unsigned short* Bfh  = (unsigned short*)(wsb + off); off += 81920 * 2;
    unsigned short* Bfl  = (unsigned short*)(wsb + off); off += 81920 * 2;
    off = (off + 255) & ~(size_t)255;
    unsigned short* partU = (unsigned short*)(wsb + off);
    const size_t avail = (ws_size > off) ? (ws_size - off) : 0;
    int CH, mode;
    if (avail >= (size_t)1024 * 19520 * 2)      { CH = 256; mode = 1; }
    else if (avail >= (size_t)512 * 19520 * 2)  { CH = 128; mode = 1; }
    else                                        { CH = 128; mode = 0; }
    const int nchunk = (N + CH - 1) / CH;

    k_prep<<<dim3(26), dim3(256), 0, stream>>>(Wq, Wk, Wv, proj, Wo,
                                               Wfh, Wfl, Pfh, Pfl, Wofh, Wofl);
    if (!mode)
        k0_zero<<<dim3((78000 + 255) / 256), dim3(256), 0, stream>>>(kvs, 78000);
    k1_feat<<<dim3(ntiles), dim3(256), 0, stream>>>(z, bq, bk, bv, Wfh, Wfl, Pfh, Pfl, tau,
                                                    qp16, v16, p16, blockmax, N);
    k2_kvs<<<dim3(4 * CH), dim3(256), 0, stream>>>(p16, gum, v16, tau, blockmax,
                                                   kvs, kssum, partU, mode, N, nchunk,
                                                   ntiles, CH);
    if (mode)
        k2r_reduce<<<dim3(325), dim3(256), 0, stream>>>(partU, kssum, Bfh, Bfl, CH);
    else
        k2b_frag<<<dim3(40), dim3(256), 0, stream>>>(kvs, Bfh, Bfl);
    k3_out<<<dim3(nblk3), dim3(512), 0, stream>>>(qp16, Bfh, Bfl, kssum,
                                                  Wofh, Wofl, bo, out, N);
}

// Round 18
// 152.460 us; speedup vs baseline: 1.2148x; 1.2148x over previous
//
#include <hip/hip_runtime.h>
#include <hip/hip_bf16.h>

// NodeFormerConv: Performer/Gumbel attention. fp32-equivalent math, fp32 output.
//   k_prep: split Wq|Wk|Wv, proj, Wo into MFMA-fragment-ordered hi/lo bf16
//   (k0   zero kvs/kssum — only in atomic-fallback mode)
//   k1   per 16-row tile, MFMA: QKV gemm (V held in regs); phi gemm; diag/rowmax/
//        exp in-register; v16/qp16/p16 staged in LDS and flushed coalesced
//   k2   MFMA accumulate; 128 chunks/head; headmax in-kernel;
//        kp = RATIO*(p16*scaleAll[tile] + NEPS); flush -> bf16 slab (or atomics)
//   k2r  (mode 1) reduce 128 bf16 slabs/head -> kssum + fragment-ordered Bfh/Bfl
//   k2b  (mode 0 only) split kvs into fragments
//   k3   per 32-row block: den up front; per head {B-frags, NUM MFMA, in-register
//        idl scale, part -> zsl[32][68], Wo MFMA for this head into o}; store o+bo

#define NEPS  1e-6f
#define RATIO 0.18257418583505536f   // 1/sqrt(30)
#define DNORM 0.35355339059327378f   // 64^-0.25

typedef __attribute__((ext_vector_type(8))) short short8;
typedef __attribute__((ext_vector_type(4))) float floatx4;

__device__ inline unsigned short f2bf(float x) {
    __hip_bfloat16 b = __float2bfloat16(x);
    return __builtin_bit_cast(unsigned short, b);
}
__device__ inline float bf2f(unsigned short h) {
    return __builtin_bit_cast(float, (unsigned int)h << 16);
}
__device__ inline void split2(float v, unsigned short& hi, unsigned short& lo) {
    unsigned short h = f2bf(v);
    hi = h; lo = f2bf(v - bf2f(h));
}

__global__ __launch_bounds__(256) void k0_zero(float* __restrict__ p, int count) {
    int id = blockIdx.x * 256 + threadIdx.x;
    if (id < count) p[id] = 0.f;
}

// ---- k_prep: fragment-ordered hi/lo splits (unchanged) ----
__global__ __launch_bounds__(256) void k_prep(
    const float* __restrict__ Wq, const float* __restrict__ Wk, const float* __restrict__ Wv,
    const float* __restrict__ proj, const float* __restrict__ Wo,
    unsigned short* __restrict__ Wfh, unsigned short* __restrict__ Wfl,
    unsigned short* __restrict__ Pfh, unsigned short* __restrict__ Pfl,
    unsigned short* __restrict__ Wofh, unsigned short* __restrict__ Wofl)
{
    const int b = blockIdx.x, t = threadIdx.x;
    if (b < 24) {
        const int slot = b * 256 + t;
        const int lane = slot & 63;
        const int ctks = slot >> 6;
        const int ct = ctks >> 1, ks = ctks & 1;
        const int col = ct * 16 + (lane & 15);
        const int k0 = ks * 32 + (lane >> 4) * 8;
        const float* W = (col < 256) ? Wq : (col < 512) ? Wk : Wv;
        const int cm = col & 255;
#pragma unroll
        for (int j = 0; j < 8; ++j) {
            float w = W[(k0 + j) * 256 + cm];
            unsigned short hi, lo; split2(w, hi, lo);
            Wfh[slot * 8 + j] = hi;
            Wfl[slot * 8 + j] = lo;
        }
    } else if (b == 24) {
        const int lane = t & 63;
        const int ctks = t >> 6;
        const int ct2 = ctks >> 1, ks = ctks & 1;
        const int m = ct2 * 16 + (lane & 15);
        const int k0 = ks * 32 + (lane >> 4) * 8;
#pragma unroll
        for (int j = 0; j < 8; ++j) {
            float p = (m < 30) ? proj[m * 64 + k0 + j] : 0.f;
            unsigned short hi, lo; split2(p, hi, lo);
            Pfh[t * 8 + j] = hi;
            Pfl[t * 8 + j] = lo;
        }
    } else {
        for (int idx = t; idx < 2048; idx += 256) {
            const int slot = idx >> 6, l = idx & 63;
            const int ct = slot >> 3, ks = slot & 7;
            const int col = ct * 16 + (l & 15);
            const int k0 = ks * 32 + (l >> 4) * 8;
#pragma unroll
            for (int j = 0; j < 8; ++j) {
                float w = Wo[(k0 + j) * 64 + col];
                unsigned short hi, lo; split2(w, hi, lo);
                Wofh[slot * 512 + l * 8 + j] = hi;
                Wofl[slot * 512 + l * 8 + j] = lo;
            }
        }
    }
}

// ---- k1: per 16-row tile; coalesced staged stores (unchanged) ----
__global__ __launch_bounds__(256) void k1_feat(
    const float* __restrict__ z,
    const float* __restrict__ bq, const float* __restrict__ bk, const float* __restrict__ bv,
    const unsigned short* __restrict__ Wfh, const unsigned short* __restrict__ Wfl,
    const unsigned short* __restrict__ Pfh, const unsigned short* __restrict__ Pfl,
    const float* __restrict__ tau,
    __hip_bfloat16* __restrict__ qp16, __hip_bfloat16* __restrict__ v16,
    __hip_bfloat16* __restrict__ p16, float* __restrict__ blockmax, int N)
{
    __shared__ alignas(16) unsigned short zh[16 * 72];
    __shared__ alignas(16) unsigned short zl_[16 * 72];
    __shared__ alignas(16) float qd[16 * 268];
    __shared__ alignas(16) float kd[16 * 268];

    unsigned short* vsS = reinterpret_cast<unsigned short*>(qd);
    unsigned short* qpS = vsS + 4096;
    unsigned short* ppS = qpS + 1920;

    const int t = threadIdx.x;
    const int n0 = blockIdx.x * 16;
    const int wave = t >> 6, lane = t & 63;
    const int l15 = lane & 15, l4 = lane >> 4;
    const float dsc = rsqrtf(tau[0]) * DNORM;

    for (int i = t; i < 1024; i += 256) {
        int r = i >> 6, c = i & 63;
        float v = (n0 + r < N) ? z[(long)(n0 + r) * 64 + c] : 0.f;
        unsigned short hi, lo; split2(v, hi, lo);
        zh[r * 72 + c] = hi;
        zl_[r * 72 + c] = lo;
    }
    __syncthreads();

    float accv[4][4];
    {
        const int abase = l15 * 72 + l4 * 8;
        short8 ah0 = *reinterpret_cast<const short8*>(&zh[abase]);
        short8 ah1 = *reinterpret_cast<const short8*>(&zh[abase + 32]);
        short8 al0 = *reinterpret_cast<const short8*>(&zl_[abase]);
        short8 al1 = *reinterpret_cast<const short8*>(&zl_[abase + 32]);
        const int row0 = l4 * 4;
#define QKV_MFMA(ci_)                                                                   \
        floatx4 acc = floatx4{0.f, 0.f, 0.f, 0.f};                                      \
        {                                                                               \
            const int ct = wave + 4 * (ci_);                                            \
            short8 bh0 = *reinterpret_cast<const short8*>(&Wfh[(ct * 2 + 0) * 512 + lane * 8]); \
            short8 bh1 = *reinterpret_cast<const short8*>(&Wfh[(ct * 2 + 1) * 512 + lane * 8]); \
            short8 bl0 = *reinterpret_cast<const short8*>(&Wfl[(ct * 2 + 0) * 512 + lane * 8]); \
            short8 bl1 = *reinterpret_cast<const short8*>(&Wfl[(ct * 2 + 1) * 512 + lane * 8]); \
            acc = __builtin_amdgcn_mfma_f32_16x16x32_bf16(ah0, bh0, acc, 0, 0, 0);      \
            acc = __builtin_amdgcn_mfma_f32_16x16x32_bf16(ah1, bh1, acc, 0, 0, 0);      \
            acc = __builtin_amdgcn_mfma_f32_16x16x32_bf16(ah0, bl0, acc, 0, 0, 0);      \
            acc = __builtin_amdgcn_mfma_f32_16x16x32_bf16(ah1, bl1, acc, 0, 0, 0);      \
            acc = __builtin_amdgcn_mfma_f32_16x16x32_bf16(al0, bh0, acc, 0, 0, 0);      \
            acc = __builtin_amdgcn_mfma_f32_16x16x32_bf16(al1, bh1, acc, 0, 0, 0);      \
        }
#pragma unroll 2
        for (int ci = 0; ci < 4; ++ci) {
            QKV_MFMA(ci)
            const int c = (wave + 4 * ci) * 16 + l15;
            const float bb = bq[c];
#pragma unroll
            for (int r = 0; r < 4; ++r) qd[(row0 + r) * 268 + c] = (acc[r] + bb) * dsc;
        }
#pragma unroll 2
        for (int ci = 4; ci < 8; ++ci) {
            QKV_MFMA(ci)
            const int c = (wave + 4 * ci) * 16 + l15 - 256;
            const float bb = bk[c];
#pragma unroll
            for (int r = 0; r < 4; ++r) kd[(row0 + r) * 268 + c] = (acc[r] + bb) * dsc;
        }
#pragma unroll
        for (int ci = 8; ci < 12; ++ci) {
            QKV_MFMA(ci)
            const int c = (wave + 4 * ci) * 16 + l15 - 512;
            const float bb = bv[c];
#pragma unroll
            for (int r = 0; r < 4; ++r) accv[ci - 8][r] = acc[r] + bb;
        }
#undef QKV_MFMA
    }
    __syncthreads();

    {
        short8 pbh[2][2], pbl[2][2];
#pragma unroll
        for (int ct2 = 0; ct2 < 2; ++ct2)
#pragma unroll
            for (int ks = 0; ks < 2; ++ks) {
                pbh[ct2][ks] = *reinterpret_cast<const short8*>(&Pfh[(ct2 * 2 + ks) * 512 + lane * 8]);
                pbl[ct2][ks] = *reinterpret_cast<const short8*>(&Pfl[(ct2 * 2 + ks) * 512 + lane * 8]);
            }
        const int h = wave;
        const int row0 = l4 * 4;
        const int rbase = l15 * 268 + h * 64 + l4 * 8;
        float xq[8], yq[8], xk[8], yk[8];
        {
            float4 a0 = *reinterpret_cast<const float4*>(&qd[rbase]);
            float4 a1 = *reinterpret_cast<const float4*>(&qd[rbase + 4]);
            float4 a2 = *reinterpret_cast<const float4*>(&qd[rbase + 32]);
            float4 a3 = *reinterpret_cast<const float4*>(&qd[rbase + 36]);
            xq[0]=a0.x; xq[1]=a0.y; xq[2]=a0.z; xq[3]=a0.w;
            xq[4]=a1.x; xq[5]=a1.y; xq[6]=a1.z; xq[7]=a1.w;
            yq[0]=a2.x; yq[1]=a2.y; yq[2]=a2.z; yq[3]=a2.w;
            yq[4]=a3.x; yq[5]=a3.y; yq[6]=a3.z; yq[7]=a3.w;
            float4 b0 = *reinterpret_cast<const float4*>(&kd[rbase]);
            float4 b1 = *reinterpret_cast<const float4*>(&kd[rbase + 4]);
            float4 b2 = *reinterpret_cast<const float4*>(&kd[rbase + 32]);
            float4 b3 = *reinterpret_cast<const float4*>(&kd[rbase + 36]);
            xk[0]=b0.x; xk[1]=b0.y; xk[2]=b0.z; xk[3]=b0.w;
            xk[4]=b1.x; xk[5]=b1.y; xk[6]=b1.z; xk[7]=b1.w;
            yk[0]=b2.x; yk[1]=b2.y; yk[2]=b2.z; yk[3]=b2.w;
            yk[4]=b3.x; yk[5]=b3.y; yk[6]=b3.z; yk[7]=b3.w;
        }
        __syncthreads();

        // ---- q side ----
        {
            float diag;
            {
                float s = 0.f;
#pragma unroll
                for (int j = 0; j < 8; ++j) s += xq[j] * xq[j] + yq[j] * yq[j];
                s += __shfl_xor(s, 16);
                s += __shfl_xor(s, 32);
                diag = 0.5f * s;
            }
            short8 ah0, al0, ah1, al1;
#pragma unroll
            for (int j = 0; j < 8; ++j) {
                unsigned short hi, lo;
                split2(xq[j], hi, lo); ah0[j] = (short)hi; al0[j] = (short)lo;
                split2(yq[j], hi, lo); ah1[j] = (short)hi; al1[j] = (short)lo;
            }
            floatx4 acc2[2];
#pragma unroll
            for (int ct2 = 0; ct2 < 2; ++ct2) {
                floatx4 acc = floatx4{0.f, 0.f, 0.f, 0.f};
                acc = __builtin_amdgcn_mfma_f32_16x16x32_bf16(ah0, pbh[ct2][0], acc, 0, 0, 0);
                acc = __builtin_amdgcn_mfma_f32_16x16x32_bf16(ah1, pbh[ct2][1], acc, 0, 0, 0);
                acc = __builtin_amdgcn_mfma_f32_16x16x32_bf16(ah0, pbl[ct2][0], acc, 0, 0, 0);
                acc = __builtin_amdgcn_mfma_f32_16x16x32_bf16(ah1, pbl[ct2][1], acc, 0, 0, 0);
                acc = __builtin_amdgcn_mfma_f32_16x16x32_bf16(al0, pbh[ct2][0], acc, 0, 0, 0);
                acc = __builtin_amdgcn_mfma_f32_16x16x32_bf16(al1, pbh[ct2][1], acc, 0, 0, 0);
                acc2[ct2] = acc;
            }
#pragma unroll
            for (int r = 0; r < 4; ++r) {
                float a1 = (l15 >= 14) ? -3.4e38f : acc2[1][r];
                float v = fmaxf(acc2[0][r], a1);
                v = fmaxf(v, __shfl_xor(v, 1));
                v = fmaxf(v, __shfl_xor(v, 2));
                v = fmaxf(v, __shfl_xor(v, 4));
                v = fmaxf(v, __shfl_xor(v, 8));
#pragma unroll
                for (int ct2 = 0; ct2 < 2; ++ct2) {
                    const int m = ct2 * 16 + l15;
                    if (m < 30)
                        qpS[(row0 + r) * 120 + h * 30 + m] =
                            f2bf(RATIO * (__expf(acc2[ct2][r] - diag - v) + NEPS));
                }
            }
        }
        // ---- k side ----
        {
            float diag;
            {
                float s = 0.f;
#pragma unroll
                for (int j = 0; j < 8; ++j) s += xk[j] * xk[j] + yk[j] * yk[j];
                s += __shfl_xor(s, 16);
                s += __shfl_xor(s, 32);
                diag = 0.5f * s;
            }
            short8 ah0, al0, ah1, al1;
#pragma unroll
            for (int j = 0; j < 8; ++j) {
                unsigned short hi, lo;
                split2(xk[j], hi, lo); ah0[j] = (short)hi; al0[j] = (short)lo;
                split2(yk[j], hi, lo); ah1[j] = (short)hi; al1[j] = (short)lo;
            }
            floatx4 acc2[2];
#pragma unroll
            for (int ct2 = 0; ct2 < 2; ++ct2) {
                floatx4 acc = floatx4{0.f, 0.f, 0.f, 0.f};
                acc = __builtin_amdgcn_mfma_f32_16x16x32_bf16(ah0, pbh[ct2][0], acc, 0, 0, 0);
                acc = __builtin_amdgcn_mfma_f32_16x16x32_bf16(ah1, pbh[ct2][1], acc, 0, 0, 0);
                acc = __builtin_amdgcn_mfma_f32_16x16x32_bf16(ah0, pbl[ct2][0], acc, 0, 0, 0);
                acc = __builtin_amdgcn_mfma_f32_16x16x32_bf16(ah1, pbl[ct2][1], acc, 0, 0, 0);
                acc = __builtin_amdgcn_mfma_f32_16x16x32_bf16(al0, pbh[ct2][0], acc, 0, 0, 0);
                acc = __builtin_amdgcn_mfma_f32_16x16x32_bf16(al1, pbh[ct2][1], acc, 0, 0, 0);
                acc2[ct2] = acc;
            }
            float vmax[4];
#pragma unroll
            for (int r = 0; r < 4; ++r) {
                float a1 = (l15 >= 14) ? -3.4e38f : acc2[1][r];
                float v = fmaxf(acc2[0][r], a1);
                v = fmaxf(v, __shfl_xor(v, 1));
                v = fmaxf(v, __shfl_xor(v, 2));
                v = fmaxf(v, __shfl_xor(v, 4));
                v = fmaxf(v, __shfl_xor(v, 8));
                vmax[r] = v;
            }
            float mv = -3.4e38f;
#pragma unroll
            for (int r = 0; r < 4; ++r)
                if (n0 + row0 + r < N) mv = fmaxf(mv, vmax[r]);
            mv = fmaxf(mv, __shfl_xor(mv, 16));
            mv = fmaxf(mv, __shfl_xor(mv, 32));
            if (lane == 0) blockmax[blockIdx.x * 4 + h] = mv;
#pragma unroll
            for (int ct2 = 0; ct2 < 2; ++ct2) {
                const int m = ct2 * 16 + l15;
                if (m < 30)
#pragma unroll
                    for (int r = 0; r < 4; ++r)
                        ppS[(row0 + r) * 120 + h * 30 + m] =
                            f2bf(__expf(acc2[ct2][r] - diag - mv));
            }
        }
#pragma unroll
        for (int ci = 8; ci < 12; ++ci) {
            const int cc = (wave + 4 * ci - 32) * 16 + l15;
#pragma unroll
            for (int r = 0; r < 4; ++r)
                vsS[(row0 + r) * 256 + cc] = f2bf(accv[ci - 8][r]);
        }
    }
    __syncthreads();

    {
        const uint4* vs4 = reinterpret_cast<const uint4*>(vsS);
        uint4* vg = reinterpret_cast<uint4*>(v16) + (long)n0 * 32;
        for (int i = t; i < 512; i += 256) {
            if (n0 + (i >> 5) < N) vg[i] = vs4[i];
        }
        const uint4* qs4 = reinterpret_cast<const uint4*>(qpS);
        uint4* qg = reinterpret_cast<uint4*>(qp16) + (long)n0 * 15;
        const uint4* ps4 = reinterpret_cast<const uint4*>(ppS);
        uint4* pg = reinterpret_cast<uint4*>(p16) + (long)n0 * 15;
        for (int i = t; i < 240; i += 256) {
            if (n0 + i / 15 < N) { qg[i] = qs4[i]; pg[i] = ps4[i]; }
        }
    }
}

// ---- k2: MFMA accumulate; 128 chunks/head; bf16 slab flush (mode 1) ----
__global__ __launch_bounds__(256) void k2_kvs(
    const __hip_bfloat16* __restrict__ p16, const float* __restrict__ gum,
    const __hip_bfloat16* __restrict__ v16, const float* __restrict__ tau,
    const float* __restrict__ blockmax,
    float* __restrict__ kvs, float* __restrict__ kssum,
    unsigned short* __restrict__ part, int mode, int N, int nchunk, int ntiles)
{
    __shared__ alignas(16) unsigned short Vt[80 * 72];
    __shared__ float kpL[64 * 33];
    __shared__ alignas(16) float geT[13 * 72];
    __shared__ float scaleAll[32];
    __shared__ float redmx[256];

    const int t = threadIdx.x;
    const int h = blockIdx.x >> 7;
    const int chunk = blockIdx.x & 127;
    const int n0 = chunk * nchunk;
    const int n1 = (n0 + nchunk < N) ? (n0 + nchunk) : N;
    const float itau = 1.0f / tau[0];
    const int wave = t >> 6, lane = t & 63;
    const int l15 = lane & 15, l4 = lane >> 4;
    const int tb0 = n0 >> 4;

    int pr_r[4], pr_m[4]; bool pvld[4];
#pragma unroll
    for (int u = 0; u < 4; ++u) {
        int i = t + 256 * u;
        pvld[u] = (i < 960);
        int ii = pvld[u] ? i : 959;
        pr_r[u] = (2 * ii) / 30;
        pr_m[u] = (2 * ii) % 30;
    }
    int gu_k[3], gu_n[3];
#pragma unroll
    for (int u = 0; u < 3; ++u) { int i = t + 256 * u; gu_k[u] = i >> 6; gu_n[u] = i & 63; }
    int v_n[8], v_dp[8];
#pragma unroll
    for (int u = 0; u < 8; ++u) { int i = t + 256 * u; v_n[u] = i >> 5; v_dp[u] = (i & 31) * 2; }

    unsigned int rp[4], rv[8];
    float rg[3];

    floatx4 acc[5][5];
#pragma unroll
    for (int q = 0; q < 5; ++q)
#pragma unroll
        for (int dt = 0; dt < 5; ++dt) acc[q][dt] = floatx4{0.f, 0.f, 0.f, 0.f};

    int mq[5], kq[5];
#pragma unroll
    for (int q = 0; q < 5; ++q) {
        int row = (wave * 5 + q) * 16 + l15;
        mq[q] = row % 30;
        kq[q] = row / 30;
    }

    if (t < 64) Vt[64 * 72 + t] = f2bf(1.0f);
    for (int i = t; i < 15 * 72; i += 256) Vt[65 * 72 + i] = 0;
    for (int i = t; i < 3 * 72; i += 256) geT[10 * 72 + i] = 0.f;

    const int ntile = (n1 > n0) ? ((n1 - n0 + 63) >> 6) : 0;

#define K2_LOAD(nb_)                                                              \
    do {                                                                          \
        _Pragma("unroll")                                                         \
        for (int u = 0; u < 4; ++u) {                                             \
            int n = (nb_) + pr_r[u]; n = (n < n1) ? n : (n1 - 1);                  \
            rp[u] = *reinterpret_cast<const unsigned int*>(                       \
                (const unsigned short*)p16 + (long)n * 120 + h * 30 + pr_m[u]);   \
        }                                                                         \
        _Pragma("unroll")                                                         \
        for (int u = 0; u < 3; ++u) {                                             \
            int n = (nb_) + gu_n[u]; n = (n < n1) ? n : (n1 - 1);                  \
            rg[u] = gum[(long)n * 40 + h * 10 + gu_k[u]];                         \
        }                                                                         \
        _Pragma("unroll")                                                         \
        for (int u = 0; u < 8; ++u) {                                             \
            int n = (nb_) + v_n[u]; n = (n < n1) ? n : (n1 - 1);                   \
            rv[u] = *reinterpret_cast<const unsigned int*>(                       \
                v16 + (long)n * 256 + h * 64 + v_dp[u]);                          \
        }                                                                         \
    } while (0)

    K2_LOAD(n0);

    // in-kernel headmax reduce
    {
        float lm = -3.4e38f;
        for (int i = t; i < ntiles; i += 256) lm = fmaxf(lm, blockmax[i * 4 + h]);
        redmx[t] = lm;
        __syncthreads();
#pragma unroll
        for (int s = 128; s > 0; s >>= 1) {
            if (t < s) redmx[t] = fmaxf(redmx[t], redmx[t + s]);
            __syncthreads();
        }
    }
    const float MX = redmx[0];
    if (t < 32) {
        int tid = tb0 + t;
        int maxtid = (N - 1) >> 4;
        if (tid > maxtid) tid = maxtid;
        scaleAll[t] = __expf(blockmax[tid * 4 + h] - MX);
    }

    for (int tt = 0; tt < ntile; ++tt) {
        const int nb = n0 + tt * 64;
        __syncthreads();
#pragma unroll
        for (int u = 0; u < 4; ++u) {
            if (pvld[u]) {
                bool ok = (nb + pr_r[u] < n1);
                float sc = scaleAll[((nb + pr_r[u]) >> 4) - tb0];
                float plo = bf2f((unsigned short)(rp[u] & 0xffffu));
                float phi = bf2f((unsigned short)(rp[u] >> 16));
                kpL[pr_r[u] * 33 + pr_m[u]]     = ok ? RATIO * (plo * sc + NEPS) : 0.f;
                kpL[pr_r[u] * 33 + pr_m[u] + 1] = ok ? RATIO * (phi * sc + NEPS) : 0.f;
            }
        }
#pragma unroll
        for (int u = 0; u < 3; ++u) {
            if (u < 2 || t < 128) {
                bool ok = (nb + gu_n[u] < n1);
                geT[gu_k[u] * 72 + gu_n[u]] = ok ? __expf(rg[u] * itau) : 0.f;
            }
        }
#pragma unroll
        for (int u = 0; u < 8; ++u) {
            bool ok = (nb + v_n[u] < n1);
            unsigned int uu = ok ? rv[u] : 0u;
            Vt[v_dp[u] * 72 + v_n[u]] = (unsigned short)(uu & 0xffffu);
            Vt[(v_dp[u] + 1) * 72 + v_n[u]] = (unsigned short)(uu >> 16);
        }
        __syncthreads();
        if (tt + 1 < ntile) K2_LOAD(nb + 64);

#pragma unroll
        for (int nh = 0; nh < 2; ++nh) {
            const int nbase = nh * 32 + l4 * 8;
            short8 b[5];
#pragma unroll
            for (int dt = 0; dt < 5; ++dt)
                b[dt] = *reinterpret_cast<const short8*>(&Vt[(dt * 16 + l15) * 72 + nbase]);
#pragma unroll
            for (int q = 0; q < 5; ++q) {
                float4 g0 = *reinterpret_cast<const float4*>(&geT[kq[q] * 72 + nbase]);
                float4 g1 = *reinterpret_cast<const float4*>(&geT[kq[q] * 72 + nbase + 4]);
                const float gg[8] = {g0.x, g0.y, g0.z, g0.w, g1.x, g1.y, g1.z, g1.w};
                short8 a;
#pragma unroll
                for (int j = 0; j < 8; ++j) {
                    float kp = kpL[(nbase + j) * 33 + mq[q]];
                    a[j] = (short)f2bf(kp * gg[j]);
                }
#pragma unroll
                for (int dt = 0; dt < 5; ++dt)
                    acc[q][dt] = __builtin_amdgcn_mfma_f32_16x16x32_bf16(a, b[dt], acc[q][dt], 0, 0, 0);
            }
        }
    }
#undef K2_LOAD

    if (mode) {
        unsigned short* slab = part + (long)blockIdx.x * 19520;
#pragma unroll
        for (int q = 0; q < 5; ++q) {
            const int kmb = (wave * 5 + q) * 16 + l4 * 4;
#pragma unroll
            for (int r = 0; r < 4; ++r) {
                const int km = kmb + r;
                if (km < 300) {
#pragma unroll
                    for (int dt = 0; dt < 4; ++dt)
                        slab[km * 64 + dt * 16 + l15] = f2bf(acc[q][dt][r]);
                    if (l15 == 0) slab[19200 + km] = f2bf(acc[q][4][r]);
                }
            }
        }
    } else {
        float* kvh = kvs + h * 19200;
#pragma unroll
        for (int q = 0; q < 5; ++q) {
            const int kmb = (wave * 5 + q) * 16 + l4 * 4;
#pragma unroll
            for (int r = 0; r < 4; ++r) {
                const int km = kmb + r;
                if (km < 300) {
#pragma unroll
                    for (int dt = 0; dt < 4; ++dt)
                        atomicAdd(&kvh[km * 64 + dt * 16 + l15], acc[q][dt][r]);
                    if (l15 == 0)
                        atomicAdd(&kssum[h * 300 + km], acc[q][4][r]);
                }
            }
        }
    }
}

// ---- k2r (mode 1): reduce 128 bf16 slabs/head -> kssum + Bfh/Bfl direct ----
__global__ __launch_bounds__(256) void k2r_reduce(
    const unsigned short* __restrict__ part, float* __restrict__ kssum,
    unsigned short* __restrict__ Bfh, unsigned short* __restrict__ Bfl)
{
    const int b = blockIdx.x, t = threadIdx.x;
    if (b >= 305) {                                    // pad zeroing
        const int p = (b - 305) * 256 + t;             // < 5120
        const int j = 6 + (p & 1);
        const int q2 = p >> 1;
        const int l15 = q2 & 15;
        const int ct = (q2 >> 4) % 40;
        const int h = q2 / 640;
        const long idx = ((long)(h * 40 + ct) * 64 + 48 + l15) * 8 + j;
        Bfh[idx] = 0; Bfl[idx] = 0;
        return;
    }
    const int o = b * 256 + t;
    if (o >= 4 * 19504) return;
    const int h = o / 19504, e = o % 19504;
    const unsigned short* p = part + (long)h * 128 * 19520 + e;
    float s = 0.f;
#pragma unroll 8
    for (int c = 0; c < 128; ++c) s += bf2f(p[(long)c * 19520]);
    if (e < 19200) {
        const int km = e >> 6, d = e & 63;
        const int k = km / 30, m = km % 30;
        const int col = k * 64 + d;
        const int ct = col >> 4;
        const int lane = ((m >> 3) << 4) | (d & 15);
        const int j = m & 7;
        const long idx = ((long)(h * 40 + ct) * 64 + lane) * 8 + j;
        unsigned short hi, lo; split2(s, hi, lo);
        Bfh[idx] = hi; Bfl[idx] = lo;
    } else if (e - 19200 < 300) {
        kssum[h * 300 + (e - 19200)] = s;
    }
}

// ---- k2b (mode 0 only) ----
__global__ __launch_bounds__(256) void k2b_frag(
    const float* __restrict__ kvs,
    unsigned short* __restrict__ Bfh, unsigned short* __restrict__ Bfl)
{
    const int slot = blockIdx.x * 256 + threadIdx.x;
    if (slot >= 10240) return;
    const int h = slot / 2560;
    const int rem = slot % 2560;
    const int ct = rem >> 6, lane = rem & 63;
    const int col = ct * 16 + (lane & 15);
    const int k = col >> 6, d = col & 63;
    const int mb = (lane >> 4) * 8;
    const float* src = kvs + h * 19200 + (k * 30 + mb) * 64 + d;
    short8 hi8, lo8;
#pragma unroll
    for (int j = 0; j < 8; ++j) {
        float v = (mb + j < 30) ? src[j * 64] : 0.f;
        unsigned short hh, ll; split2(v, hh, ll);
        hi8[j] = (short)hh; lo8[j] = (short)ll;
    }
    *reinterpret_cast<short8*>(&Bfh[(long)slot * 8]) = hi8;
    *reinterpret_cast<short8*>(&Bfl[(long)slot * 8]) = lo8;
}

// ---- k3: den up front; per head {B-frags, NUM MFMA, idl in-reg, zsl, Wo MFMA} ----
__global__ __launch_bounds__(512) void k3_out(
    const __hip_bfloat16* __restrict__ qp16,
    const unsigned short* __restrict__ Bfh, const unsigned short* __restrict__ Bfl,
    const float* __restrict__ kssum,
    const unsigned short* __restrict__ Wofh, const unsigned short* __restrict__ Wofl,
    const float* __restrict__ bo, float* __restrict__ out, int N)
{
    __shared__ alignas(16) unsigned short qpall[32 * 136];
    __shared__ float ksall[1200];
    __shared__ float idla[4 * 320];
    __shared__ alignas(16) float part[2][32][68];
    __shared__ alignas(16) float zsl[32][68];

    const int t = threadIdx.x;
    const int n0 = blockIdx.x * 32;
    const int wave = t >> 6, lane = t & 63;
    const int g = wave & 3, khalf = wave >> 2;
    const int l15 = lane & 15, l4 = lane >> 4;

    for (int i = t; i < 1200; i += 512) ksall[i] = kssum[i];
    for (int i = t; i < 32 * 60; i += 512) {
        int rr = i / 60, dw = i % 60;
        int n = n0 + rr; if (n >= N) n = N - 1;
        unsigned int u = *reinterpret_cast<const unsigned int*>(
            (const unsigned short*)qp16 + (long)n * 120 + dw * 2);
        int h = dw / 15, md = (dw % 15) * 2;
        qpall[rr * 136 + h * 32 + md] = (unsigned short)(u & 0xffffu);
        qpall[rr * 136 + h * 32 + md + 1] = (unsigned short)(u >> 16);
    }
    __syncthreads();

    for (int i = t; i < 1280; i += 512) {
        int h = i / 320, rem = i % 320;
        int rr = rem / 10, kk = rem % 10;
        const unsigned short* qr = &qpall[rr * 136 + h * 32];
        const float* kr = &ksall[h * 300 + kk * 30];
        float s = 0.f;
#pragma unroll
        for (int m = 0; m < 30; ++m) s += bf2f(qr[m]) * kr[m];
        idla[i] = 1.0f / s;
    }
    __syncthreads();

    floatx4 o = floatx4{0.f, 0.f, 0.f, 0.f};

    for (int h = 0; h < 4; ++h) {
        short8 bh[5], bl[5];
#pragma unroll
        for (int q = 0; q < 5; ++q) {
            const int ct = (khalf * 5 + q) * 4 + g;
            const long off = ((long)(h * 40 + ct) * 64 + lane) * 8;
            bh[q] = *reinterpret_cast<const short8*>(Bfh + off);
            bl[q] = *reinterpret_cast<const short8*>(Bfl + off);
        }
        short8 aQ[2];
#pragma unroll
        for (int rt = 0; rt < 2; ++rt) {
            const unsigned int* qrow = reinterpret_cast<const unsigned int*>(
                &qpall[(rt * 16 + l15) * 136 + h * 32 + l4 * 8]);
            short8 a;
#pragma unroll
            for (int jj = 0; jj < 4; ++jj) {
                unsigned int u = qrow[jj];
                a[jj * 2] = (short)(u & 0xffffu);
                a[jj * 2 + 1] = (short)(u >> 16);
            }
            if (l4 == 3) { a[6] = 0; a[7] = 0; }
            aQ[rt] = a;
        }
        floatx4 acc[2][5];
#pragma unroll
        for (int rt = 0; rt < 2; ++rt)
#pragma unroll
            for (int q = 0; q < 5; ++q) acc[rt][q] = floatx4{0.f, 0.f, 0.f, 0.f};
#pragma unroll
        for (int q = 0; q < 5; ++q) {
            acc[0][q] = __builtin_amdgcn_mfma_f32_16x16x32_bf16(aQ[0], bh[q], acc[0][q], 0, 0, 0);
            acc[0][q] = __builtin_amdgcn_mfma_f32_16x16x32_bf16(aQ[0], bl[q], acc[0][q], 0, 0, 0);
            acc[1][q] = __builtin_amdgcn_mfma_f32_16x16x32_bf16(aQ[1], bh[q], acc[1][q], 0, 0, 0);
            acc[1][q] = __builtin_amdgcn_mfma_f32_16x16x32_bf16(aQ[1], bl[q], acc[1][q], 0, 0, 0);
        }
#pragma unroll
        for (int rt = 0; rt < 2; ++rt)
#pragma unroll
            for (int r = 0; r < 4; ++r) {
                const int row = rt * 16 + l4 * 4 + r;
                float s = 0.f;
#pragma unroll
                for (int q = 0; q < 5; ++q)
                    s += acc[rt][q][r] * idla[h * 320 + row * 10 + khalf * 5 + q];
                part[khalf][row][g * 16 + l15] = s;
            }
        __syncthreads();                         // [A] part ready, prev Wo reads done
        {
            const int row = t >> 4, d4 = t & 15;
            float4 p0 = *reinterpret_cast<const float4*>(&part[0][row][d4 * 4]);
            float4 p1 = *reinterpret_cast<const float4*>(&part[1][row][d4 * 4]);
            float4 zv;
            zv.x = 0.1f * (p0.x + p1.x); zv.y = 0.1f * (p0.y + p1.y);
            zv.z = 0.1f * (p0.z + p1.z); zv.w = 0.1f * (p0.w + p1.w);
            *reinterpret_cast<float4*>(&zsl[row][d4 * 4]) = zv;
        }
        __syncthreads();                         // [B] zsl ready, part free
#pragma unroll
        for (int ks = 0; ks < 2; ++ks) {
            const float* zr = &zsl[khalf * 16 + l15][ks * 32 + l4 * 8];
            float4 x0 = *reinterpret_cast<const float4*>(zr);
            float4 x1 = *reinterpret_cast<const float4*>(zr + 4);
            float xv[8] = {x0.x, x0.y, x0.z, x0.w, x1.x, x1.y, x1.z, x1.w};
            short8 ah, al;
#pragma unroll
            for (int j = 0; j < 8; ++j) {
                unsigned short hi, lo; split2(xv[j], hi, lo);
                ah[j] = (short)hi; al[j] = (short)lo;
            }
            const int slot = g * 8 + h * 2 + ks;
            short8 wbh = *reinterpret_cast<const short8*>(&Wofh[slot * 512 + lane * 8]);
            short8 wbl = *reinterpret_cast<const short8*>(&Wofl[slot * 512 + lane * 8]);
            o = __builtin_amdgcn_mfma_f32_16x16x32_bf16(ah, wbh, o, 0, 0, 0);
            o = __builtin_amdgcn_mfma_f32_16x16x32_bf16(ah, wbl, o, 0, 0, 0);
            o = __builtin_amdgcn_mfma_f32_16x16x32_bf16(al, wbh, o, 0, 0, 0);
        }
    }
    {
        const int col = g * 16 + l15;
        const float bb = bo[col];
#pragma unroll
        for (int r = 0; r < 4; ++r) {
            const int n = n0 + khalf * 16 + l4 * 4 + r;
            if (n < N) out[(long)n * 64 + col] = o[r] + bb;
        }
    }
}

extern "C" void kernel_launch(void* const* d_in, const int* in_sizes, int n_in,
                              void* d_out, int out_size, void* d_ws, size_t ws_size,
                              hipStream_t stream)
{
    const float* z    = (const float*)d_in[0];
    const float* Wq   = (const float*)d_in[1];
    const float* bq   = (const float*)d_in[2];
    const float* Wk   = (const float*)d_in[3];
    const float* bk   = (const float*)d_in[4];
    const float* Wv   = (const float*)d_in[5];
    const float* bv   = (const float*)d_in[6];
    const float* Wo   = (const float*)d_in[7];
    const float* bo   = (const float*)d_in[8];
    const float* proj = (const float*)d_in[9];
    const float* gum  = (const float*)d_in[10];
    const float* tau  = (const float*)d_in[11];
    float* out = (float*)d_out;

    const int N = in_sizes[0] / 64;          // 50000
    const int ntiles = (N + 15) / 16;        // 3125
    const int nblk3  = (N + 31) / 32;        // 1563
    const int nchunk = (N + 127) / 128;      // 391

    char* wsb = (char*)d_ws;
    size_t off = 0;
    __hip_bfloat16* qp16 = (__hip_bfloat16*)(wsb);
    off += ((size_t)N * 120 * 2 + 255) & ~(size_t)255;
    __hip_bfloat16* v16 = (__hip_bfloat16*)(wsb + off);
    off += ((size_t)N * 256 * 2 + 255) & ~(size_t)255;
    __hip_bfloat16* p16 = (__hip_bfloat16*)(wsb + off);
    off += ((size_t)N * 120 * 2 + 255) & ~(size_t)255;
    float* kvs      = (float*)(wsb + off);
    float* kssum    = kvs + 76800;
    float* headmax  = kssum + 1200;
    float* blockmax = headmax + 4;
    off += ((size_t)(76800 + 1200 + 4 + (size_t)ntiles * 4) * 4 + 255) & ~(size_t)255;
    unsigned short* Wfh = (unsigned short*)(wsb + off); off += 49152 * 2;
    unsigned short* Wfl = (unsigned short*)(wsb + off); off += 49152 * 2;
    unsigned short* Pfh = (unsigned short*)(wsb + off); off += 2048 * 2;
    unsigned short* Pfl = (unsigned short*)(wsb + off); off += 2048 * 2;
    unsigned short* Wofh = (unsigned short*)(wsb + off); off += 16384 * 2;
    unsigned short* Wofl = (unsigned short*)(wsb + off); off += 16384 * 2;
    unsigned short* Bfh  = (unsigned short*)(wsb + off); off += 81920 * 2;
    unsigned short* Bfl  = (unsigned short*)(wsb + off); off += 81920 * 2;
    off = (off + 255) & ~(size_t)255;
    unsigned short* partU = (unsigned short*)(wsb + off);
    const size_t part_bytes = (size_t)512 * 19520 * 2;
    const int mode = (ws_size >= off + part_bytes) ? 1 : 0;

    k_prep<<<dim3(26), dim3(256), 0, stream>>>(Wq, Wk, Wv, proj, Wo,
                                               Wfh, Wfl, Pfh, Pfl, Wofh, Wofl);
    if (!mode)
        k0_zero<<<dim3((78000 + 255) / 256), dim3(256), 0, stream>>>(kvs, 78000);
    k1_feat<<<dim3(ntiles), dim3(256), 0, stream>>>(z, bq, bk, bv, Wfh, Wfl, Pfh, Pfl, tau,
                                                    qp16, v16, p16, blockmax, N);
    k2_kvs<<<dim3(512), dim3(256), 0, stream>>>(p16, gum, v16, tau, blockmax,
                                                kvs, kssum, partU, mode, N, nchunk, ntiles);
    if (mode)
        k2r_reduce<<<dim3(325), dim3(256), 0, stream>>>(partU, kssum, Bfh, Bfl);
    else
        k2b_frag<<<dim3(40), dim3(256), 0, stream>>>(kvs, Bfh, Bfl);
    k3_out<<<dim3(nblk3), dim3(512), 0, stream>>>(qp16, Bfh, Bfl, kssum,
                                                  Wofh, Wofl, bo, out, N);
}